// Round 5
// baseline (841.396 us; speedup 1.0000x reference)
//
#include <hip/hip_runtime.h>

#define HH 96
#define WW 96
#define HW 9216
#define NPIX 18432      // B*H*W, B=2
#define OMC 216

typedef __attribute__((ext_vector_type(8))) short short8x;       // MFMA bf16 frag
typedef __attribute__((ext_vector_type(8))) unsigned short ushort8x;
typedef __attribute__((ext_vector_type(4))) float f32x4;

__device__ __forceinline__ f32x4 mfma16(short8x a, short8x b, f32x4 c) {
    return __builtin_amdgcn_mfma_f32_16x16x32_bf16(a, b, c, 0, 0, 0);
}
__device__ __forceinline__ unsigned short f2bf(float f) {
    unsigned int u = __float_as_uint(f);
    u = (u + 0x7FFFu + ((u >> 16) & 1u)) >> 16;   // RNE (finite values)
    return (unsigned short)u;
}
__device__ __forceinline__ float bf2f(unsigned short b) {
    return __uint_as_float((unsigned int)b << 16);
}
__device__ __forceinline__ void split2(float v, unsigned short& h, unsigned short& l) {
    h = f2bf(v);
    l = f2bf(v - bf2f(h));
}

// ---------------------------------------------------------------------------
// NCHW fp32 -> r1f (fp32 NHWC, gather src), diff=R1-Q0 (hi/lo bf16, conv1 in),
// Q0 -> cat channels (hi at 128..255, lo at 384..511). 64 pixels per block.
__global__ __launch_bounds__(256) void prep_acts(
    const float* __restrict__ R1, const float* __restrict__ Q0,
    float* __restrict__ r1f,             // [NPIX][128] fp32
    unsigned short* __restrict__ diffb,  // [NPIX][256] hi|lo
    unsigned short* __restrict__ cat)    // [NPIX][512]
{
    __shared__ float tR[128][64];
    __shared__ float tQ[128][64];
    int tid = threadIdx.x;
    int p0  = blockIdx.x * 64;
    int b   = p0 / HW;
    int rem0 = p0 % HW;

    for (int e = tid; e < 2048; e += 256) {          // 128 ch x 16 float4
        int c = e >> 4, j = e & 15;
        size_t base = ((size_t)(b * 128 + c)) * HW + rem0;
        *(float4*)&tR[c][j * 4] = *(const float4*)(R1 + base + j * 4);
        *(float4*)&tQ[c][j * 4] = *(const float4*)(Q0 + base + j * 4);
    }
    __syncthreads();

    int p = tid & 63, half = tid >> 6;   // half 0..3
    int c0 = half * 32;
    size_t px = (size_t)p0 + p;
    float rv[32];
    ushort8x dh[4], dl[4], qh[4], ql[4];
    #pragma unroll
    for (int cc = 0; cc < 32; ++cc) {
        float r = tR[c0 + cc][p], q = tQ[c0 + cc][p];
        rv[cc] = r;
        unsigned short h, l;
        split2(r - q, h, l); dh[cc >> 3][cc & 7] = h; dl[cc >> 3][cc & 7] = l;
        split2(q, h, l);     qh[cc >> 3][cc & 7] = h; ql[cc >> 3][cc & 7] = l;
    }
    #pragma unroll
    for (int i = 0; i < 8; ++i)
        *(float4*)&r1f[px * 128 + c0 + i * 4] = *(float4*)&rv[i * 4];
    #pragma unroll
    for (int i = 0; i < 4; ++i) {
        *(ushort8x*)&diffb[px * 256 +       c0 + i * 8] = dh[i];
        *(ushort8x*)&diffb[px * 256 + 128 + c0 + i * 8] = dl[i];
        *(ushort8x*)&cat [px * 512 + 128 + c0 + i * 8] = qh[i];
        *(ushort8x*)&cat [px * 512 + 384 + c0 + i * 8] = ql[i];
    }
}

// ---------------------------------------------------------------------------
// Weight repack to bf16 hi/lo planes.
// p1/p2: [2][9][128][128]  (tap-major, [t][o][ci])
// pom:   [2][9][256][128]  (o padded to 256)
// prq:   [2][9][128][256]
// pdcn:  [2][128][1152]    K-order = k*128+ci (tap-major within row)
__global__ __launch_bounds__(256) void prep_w(
    const float* __restrict__ w1, const float* __restrict__ w2,
    const float* __restrict__ wom, const float* __restrict__ bom,
    const float* __restrict__ wrq, const float* __restrict__ wdcn,
    unsigned short* __restrict__ p1, unsigned short* __restrict__ p2,
    unsigned short* __restrict__ pom, unsigned short* __restrict__ prq,
    unsigned short* __restrict__ pdcn, float* __restrict__ bomp)
{
    int idx = blockIdx.x * 256 + threadIdx.x;
    unsigned short h, l;
    if (idx < 147456) {                   // 9*128*128
        int t = idx / 16384, o = (idx >> 7) & 127, ci = idx & 127;
        int src = (o * 128 + ci) * 9 + t;
        split2(w1[src], h, l);  p1[idx] = h;  p1[idx + 147456] = l;
        split2(w2[src], h, l);  p2[idx] = h;  p2[idx + 147456] = l;
        int dd = o * 1152 + t * 128 + ci;
        split2(wdcn[src], h, l); pdcn[dd] = h; pdcn[dd + 147456] = l;
    }
    if (idx < 294912) {
        { // om
            int t = idx / 32768, o = (idx >> 7) & 255, ci = idx & 127;
            float v = (o < OMC) ? wom[(o * 128 + ci) * 9 + t] : 0.f;
            split2(v, h, l); pom[idx] = h; pom[idx + 294912] = l;
        }
        { // rq
            int t = idx / 32768, o = (idx >> 8) & 127, ci = idx & 255;
            split2(wrq[(o * 256 + ci) * 9 + t], h, l);
            prq[idx] = h; prq[idx + 294912] = l;
        }
    }
    if (idx < 256) bomp[idx] = (idx < OMC) ? bom[idx] : 0.f;
}

// ---------------------------------------------------------------------------
// Shift-GEMM 3x3 conv, pad=1, hi/lo bf16 NHWC in (row = [CIN hi][CIN lo]),
// split weights, MFMA 16x16x32, 3-product compensation.
// Block: 4 waves, tile 32 px x 64 outs; wave tile 16 px x 32 outs.
// Register-stages full 128-K chunks (24 fragments) before issuing MFMAs.
// MODE 0: bf16 hi/lo out, row stride 2*COUTP. MODE 1: single-bf16 [pix][216].
// MODE 2: fp32 NCHW.
template<int CIN, int COUTP, int MODE, bool RELU>
__global__ __launch_bounds__(256, 3) void conv_mfma(
    const unsigned short* __restrict__ in,   // [NPIX][2*CIN]
    const unsigned short* __restrict__ wpk,  // [2][9][COUTP][CIN]
    const float* __restrict__ bias,          // [COUTP]
    void* __restrict__ outv)
{
    const size_t WPLANE = (size_t)9 * COUTP * CIN;
    int tid = threadIdx.x;
    int wid = tid >> 6, lane = tid & 63;
    int r = lane & 15, q = lane >> 4;
    int mg = wid >> 1;                       // pixel group (16 px)
    int ng = wid & 1;                        // out group (32 outs)
    int pblk = blockIdx.x * 32;
    int n0 = blockIdx.y * 64 + ng * 32;
    int b = pblk / HW;
    int prem = pblk % HW;
    int pg = prem + mg * 16;

    f32x4 acc[2] = {};

    #pragma unroll
    for (int t = 0; t < 9; ++t) {
        const int dy = t / 3 - 1, dx = t % 3 - 1;
        int yg = pg / 96 + dy;
        int xg = pg % 96 + r + dx;
        bool av = ((unsigned)yg < 96u) && ((unsigned)xg < 96u);
        const unsigned short* ap = in + ((size_t)b * HW + yg * 96 + xg) * (2 * CIN) + q * 8;
        const unsigned short* wt = wpk + ((size_t)t * COUTP + n0 + r) * CIN + q * 8;

        #pragma unroll
        for (int ch = 0; ch < CIN / 128; ++ch) {
            short8x ah[4], al[4], w0h[4], w1h[4], w0l[4], w1l[4];
            #pragma unroll
            for (int kc = 0; kc < 4; ++kc) {
                const int ko = ch * 128 + kc * 32;
                ah[kc] = short8x{}; al[kc] = short8x{};
                if (av) {
                    ah[kc] = *(const short8x*)(ap + ko);
                    al[kc] = *(const short8x*)(ap + CIN + ko);
                }
                w0h[kc] = *(const short8x*)(wt + ko);
                w1h[kc] = *(const short8x*)(wt + (size_t)16 * CIN + ko);
                w0l[kc] = *(const short8x*)(wt + WPLANE + ko);
                w1l[kc] = *(const short8x*)(wt + WPLANE + (size_t)16 * CIN + ko);
            }
            #pragma unroll
            for (int kc = 0; kc < 4; ++kc) {
                acc[0] = mfma16(ah[kc], w0h[kc], acc[0]);
                acc[1] = mfma16(ah[kc], w1h[kc], acc[1]);
                acc[0] = mfma16(al[kc], w0h[kc], acc[0]);
                acc[1] = mfma16(al[kc], w1h[kc], acc[1]);
                acc[0] = mfma16(ah[kc], w0l[kc], acc[0]);
                acc[1] = mfma16(ah[kc], w1l[kc], acc[1]);
            }
        }
    }

    #pragma unroll
    for (int ni = 0; ni < 2; ++ni) {
        int o = n0 + ni * 16 + r;
        float bv = bias[o];
        #pragma unroll
        for (int j = 0; j < 4; ++j) {
            int pixel = pblk + mg * 16 + q * 4 + j;
            float v = acc[ni][j] + bv;
            if (RELU) v = fmaxf(v, 0.f);
            if (MODE == 0) {
                unsigned short h, l; split2(v, h, l);
                ((unsigned short*)outv)[(size_t)pixel * 2 * COUTP + o] = h;
                ((unsigned short*)outv)[(size_t)pixel * 2 * COUTP + COUTP + o] = l;
            } else if (MODE == 1) {
                if (o < OMC) ((unsigned short*)outv)[(size_t)pixel * OMC + o] = f2bf(v);
            } else {
                int bb = pixel / HW, rm = pixel % HW;
                ((float*)outv)[((size_t)bb * 128 + o) * HW + rm] = v;
            }
        }
    }
}

// ---------------------------------------------------------------------------
// Deformable conv v2, split precision. 16 pixels/block, 256 threads.
// Phase AB (fused): per (pixel, group, tap) compute bilinear corners from bf16
// offsets, gather 16 fp32 channels, scale by mask*corner weights, split hi/lo
// into XOR-swizzled LDS (K-order = k*128+c, matching pdcn). Phase C: 3-product
// MFMA over K=1152, register-staged in 128-K chunks; relu(acc+bias) -> cat.
__global__ __launch_bounds__(256) void deform_mfma(
    const float* __restrict__ xf,            // [NPIX][128] fp32 NHWC (R1)
    const unsigned short* __restrict__ omf,  // [NPIX][216] bf16
    const unsigned short* __restrict__ wpk,  // [2][128][1152]
    const float* __restrict__ bias,          // [128]
    unsigned short* __restrict__ cat)        // [NPIX][512]
{
    __shared__ __align__(16) unsigned short s_vh[16][1152];
    __shared__ __align__(16) unsigned short s_vl[16][1152];

    int tid = threadIdx.x;
    int pix0 = blockIdx.x * 16;
    int b = pix0 / HW;

    for (int e = tid; e < 1152; e += 256) {
        int p = e / 72, gk = e % 72;
        int pix = pix0 + p;
        int rem = pix % HW;
        int hh = rem / 96, ww = rem % 96;
        int g = gk / 9, k = gk % 9;
        const unsigned short* op = omf + (size_t)pix * OMC;
        float dy = bf2f(op[g * 18 + 2 * k]);
        float dx = bf2f(op[g * 18 + 2 * k + 1]);
        float mr = bf2f(op[144 + g * 9 + k]);
        float m = 1.f / (1.f + __expf(-mr));
        float py = dy + (float)(k / 3) + (float)hh - 1.f;
        float px = dx + (float)(k % 3) + (float)ww - 1.f;
        float fy = floorf(py), fx = floorf(px);
        int y0 = (int)fy, x0 = (int)fx;
        float ly = py - fy, lx = px - fx;
        float cw[4] = {(1.f - ly) * (1.f - lx), (1.f - ly) * lx,
                       ly * (1.f - lx), ly * lx};
        const float* cp[4];
        #pragma unroll
        for (int j = 0; j < 4; ++j) {
            int yy = y0 + (j >> 1), xx = x0 + (j & 1);
            bool valid = (yy >= 0) && (yy < HH) && (xx >= 0) && (xx < WW);
            int yc = yy < 0 ? 0 : (yy > 95 ? 95 : yy);
            int xc = xx < 0 ? 0 : (xx > 95 ? 95 : xx);
            cp[j] = xf + ((size_t)(b * HW + yc * 96 + xc)) * 128 + g * 16;
            cw[j] = valid ? cw[j] * m : 0.f;
        }
        int swz = (p & 7) << 3;
        int i0 = k * 128 + g * 16;
        ushort8x vh[2], vl[2];
        #pragma unroll
        for (int cq = 0; cq < 4; ++cq) {
            float4 v0 = *(const float4*)(cp[0] + cq * 4);
            float4 v1 = *(const float4*)(cp[1] + cq * 4);
            float4 v2 = *(const float4*)(cp[2] + cq * 4);
            float4 v3 = *(const float4*)(cp[3] + cq * 4);
            float vv[4] = {
                cw[0]*v0.x + cw[1]*v1.x + cw[2]*v2.x + cw[3]*v3.x,
                cw[0]*v0.y + cw[1]*v1.y + cw[2]*v2.y + cw[3]*v3.y,
                cw[0]*v0.z + cw[1]*v1.z + cw[2]*v2.z + cw[3]*v3.z,
                cw[0]*v0.w + cw[1]*v1.w + cw[2]*v2.w + cw[3]*v3.w};
            #pragma unroll
            for (int cc = 0; cc < 4; ++cc) {
                unsigned short h, l;
                split2(vv[cc], h, l);
                int ei = cq * 4 + cc;
                vh[ei >> 3][ei & 7] = h;
                vl[ei >> 3][ei & 7] = l;
            }
        }
        *(ushort8x*)&s_vh[p][(i0    ) ^ swz] = vh[0];
        *(ushort8x*)&s_vh[p][(i0 + 8) ^ swz] = vh[1];
        *(ushort8x*)&s_vl[p][(i0    ) ^ swz] = vl[0];
        *(ushort8x*)&s_vl[p][(i0 + 8) ^ swz] = vl[1];
    }
    __syncthreads();

    // Phase C: M=16 pixels x N=128 outs; each wave 32 outs; 128-K chunks.
    int wid = tid >> 6, lane = tid & 63;
    int r = lane & 15, q = lane >> 4;
    int n0 = wid * 32;
    f32x4 acc0 = {}, acc1 = {};
    const unsigned short* wb = wpk + (size_t)(n0 + r) * 1152 + q * 8;
    int swz = (r & 7) << 3;
    #pragma unroll
    for (int ch = 0; ch < 9; ++ch) {
        short8x ah[4], al[4], b0h[4], b1h[4], b0l[4], b1l[4];
        #pragma unroll
        for (int k2 = 0; k2 < 4; ++k2) {
            const int kc = ch * 4 + k2;
            int e0 = (kc * 32 + q * 8) ^ swz;
            ah[k2]  = *(const short8x*)&s_vh[r][e0];
            al[k2]  = *(const short8x*)&s_vl[r][e0];
            b0h[k2] = *(const short8x*)(wb + kc * 32);
            b1h[k2] = *(const short8x*)(wb + (size_t)16 * 1152 + kc * 32);
            b0l[k2] = *(const short8x*)(wb + 147456 + kc * 32);
            b1l[k2] = *(const short8x*)(wb + 147456 + (size_t)16 * 1152 + kc * 32);
        }
        #pragma unroll
        for (int k2 = 0; k2 < 4; ++k2) {
            acc0 = mfma16(ah[k2], b0h[k2], acc0);
            acc1 = mfma16(ah[k2], b1h[k2], acc1);
            acc0 = mfma16(al[k2], b0h[k2], acc0);
            acc1 = mfma16(al[k2], b1h[k2], acc1);
            acc0 = mfma16(ah[k2], b0l[k2], acc0);
            acc1 = mfma16(ah[k2], b1l[k2], acc1);
        }
    }
    #pragma unroll
    for (int ni = 0; ni < 2; ++ni) {
        f32x4 A = ni ? acc1 : acc0;
        int o = n0 + ni * 16 + r;
        float bv = bias[o];
        #pragma unroll
        for (int j = 0; j < 4; ++j) {
            int pixel = pix0 + q * 4 + j;
            float v = fmaxf(A[j] + bv, 0.f);
            unsigned short h, l;
            split2(v, h, l);
            cat[(size_t)pixel * 512 + o] = h;
            cat[(size_t)pixel * 512 + 256 + o] = l;
        }
    }
}

// ---------------------------------------------------------------------------
extern "C" void kernel_launch(void* const* d_in, const int* in_sizes, int n_in,
                              void* d_out, int out_size, void* d_ws, size_t ws_size,
                              hipStream_t stream) {
    const float* R1    = (const float*)d_in[0];
    const float* Q0    = (const float*)d_in[1];
    const float* w1    = (const float*)d_in[2];
    const float* b1    = (const float*)d_in[3];
    const float* w2    = (const float*)d_in[4];
    const float* b2    = (const float*)d_in[5];
    const float* w_om  = (const float*)d_in[6];
    const float* b_om  = (const float*)d_in[7];
    const float* w_dcn = (const float*)d_in[8];
    const float* b_dcn = (const float*)d_in[9];
    const float* w_rq  = (const float*)d_in[10];
    const float* b_rq  = (const float*)d_in[11];
    float* outp = (float*)d_out;

    // Arena: ~48.9 MiB — omf aliases t1 (dead after conv2), t2 aliases diffb.
    char* w = (char*)d_ws;
    float*          r1f   = (float*)w;          w += (size_t)NPIX * 128 * 4;  // 9.44 MB
    unsigned short* diffb = (unsigned short*)w; w += (size_t)NPIX * 256 * 2;  // 9.44 MB (also t2)
    unsigned short* t1    = (unsigned short*)w; w += (size_t)NPIX * 256 * 2;  // 9.44 MB (also omf)
    unsigned short* catb  = (unsigned short*)w; w += (size_t)NPIX * 512 * 2;  // 18.87 MB
    unsigned short* p1    = (unsigned short*)w; w += 2 * 147456 * 2;
    unsigned short* p2    = (unsigned short*)w; w += 2 * 147456 * 2;
    unsigned short* pdcn  = (unsigned short*)w; w += 2 * 147456 * 2;
    unsigned short* pom   = (unsigned short*)w; w += 2 * 294912 * 2;
    unsigned short* prq   = (unsigned short*)w; w += 2 * 294912 * 2;
    float*          bomp  = (float*)w;          w += 256 * 4;
    unsigned short* t2    = diffb;   // diff dead after conv1
    unsigned short* omf   = t1;      // t1 dead after conv2; bf16 [NPIX][216]

    prep_acts<<<288, 256, 0, stream>>>(R1, Q0, r1f, diffb, catb);
    prep_w<<<1152, 256, 0, stream>>>(w1, w2, w_om, b_om, w_rq, w_dcn,
                                     p1, p2, pom, prq, pdcn, bomp);

    conv_mfma<128, 128, 0, true ><<<dim3(576, 2), 256, 0, stream>>>(diffb, p1, b1, t1);
    conv_mfma<128, 128, 0, true ><<<dim3(576, 2), 256, 0, stream>>>(t1,    p2, b2, t2);
    conv_mfma<128, 256, 1, false><<<dim3(576, 4), 256, 0, stream>>>(t2,   pom, bomp, omf);

    deform_mfma<<<1152, 256, 0, stream>>>(r1f, omf, pdcn, b_dcn, catb);

    conv_mfma<256, 128, 2, true ><<<dim3(576, 2), 256, 0, stream>>>(catb, prq, b_rq, outp);
}